// Round 2
// baseline (609.854 us; speedup 1.0000x reference)
//
#include <hip/hip_runtime.h>

// out[b,o] = max_i min(m[b,i], clamp(w[i,o],0,1))
// B=1024, IN=512, OUT=256, fp32. VALU-bound tropical matmul (no MFMA path).

constexpr int IN  = 512;
constexpr int OUT = 256;
constexpr int RB  = 2;    // rows of B per block  -> grid = B/RB = 512 blocks
constexpr int KC  = 32;   // k-chunk of w held in registers (double-buffered)

__global__ __launch_bounds__(256, 2)
void minmax_kernel(const float* __restrict__ m,
                   const float* __restrict__ w,
                   float* __restrict__ out) {
  __shared__ float m_s[RB][IN];              // 2*512*4 = 4 KB
  const int tid = threadIdx.x;               // tid == output column (OUT==256)
  const int b0  = blockIdx.x * RB;

  // Stage RB m-rows into LDS, vectorized float4. RB*IN/4 = 256 float4 = 1/thread.
  {
    const float4* src = reinterpret_cast<const float4*>(m + (size_t)b0 * IN);
    float4*       dst = reinterpret_cast<float4*>(&m_s[0][0]);
    dst[tid] = src[tid];
  }
  __syncthreads();

  float acc[RB];
#pragma unroll
  for (int r = 0; r < RB; ++r) acc[r] = -__builtin_inff();

  const float* wp = w + tid;  // this thread's column base

  // LOAD: fetch KC strided w values (coalesced 256B per k across the wave),
  // clamp to [0,1] (fmin(fmax) -> v_med3_f32).
  auto LOAD = [&](float (&buf)[KC], int kc) {
#pragma unroll
    for (int k = 0; k < KC; ++k) {
      float x = wp[(size_t)(kc + k) * OUT];
      buf[k] = fminf(fmaxf(x, 0.0f), 1.0f);
    }
  };

  // COMPUTE: acc[r] = max(acc[r], min(m_s[r][kc+k], buf[k])) over the chunk.
  // m_s reads are wave-uniform addresses -> LDS broadcast, conflict-free.
  auto COMPUTE = [&](const float (&buf)[KC], int kc) {
#pragma unroll
    for (int r = 0; r < RB; ++r) {
#pragma unroll
      for (int k4 = 0; k4 < KC; k4 += 4) {
        float4 mv = *reinterpret_cast<const float4*>(&m_s[r][kc + k4]);
        acc[r] = fmaxf(acc[r], fminf(mv.x, buf[k4 + 0]));
        acc[r] = fmaxf(acc[r], fminf(mv.y, buf[k4 + 1]));
        acc[r] = fmaxf(acc[r], fminf(mv.z, buf[k4 + 2]));
        acc[r] = fmaxf(acc[r], fminf(mv.w, buf[k4 + 3]));
      }
    }
  };

  float wcA[KC], wcB[KC];   // two named buffers: all indices compile-time (no scratch)
  LOAD(wcA, 0);
#pragma unroll
  for (int kc = 0; kc < IN; kc += 2 * KC) {
    LOAD(wcB, kc + KC);                     // prefetch next chunk
    COMPUTE(wcA, kc);
    if (kc + 2 * KC < IN) LOAD(wcA, kc + 2 * KC);
    COMPUTE(wcB, kc + KC);
  }

#pragma unroll
  for (int r = 0; r < RB; ++r)
    out[(size_t)(b0 + r) * OUT + tid] = acc[r];
}

extern "C" void kernel_launch(void* const* d_in, const int* in_sizes, int n_in,
                              void* d_out, int out_size, void* d_ws, size_t ws_size,
                              hipStream_t stream) {
  (void)n_in; (void)out_size; (void)d_ws; (void)ws_size;
  const float* m = (const float*)d_in[0];
  const float* w = (const float*)d_in[1];
  float* out = (float*)d_out;
  const int B = in_sizes[0] / IN;           // 1024
  dim3 grid(B / RB);                        // 512 blocks
  minmax_kernel<<<grid, 256, 0, stream>>>(m, w, out);
}

// Round 4
// 97.098 us; speedup vs baseline: 6.2808x; 6.2808x over previous
//
#include <hip/hip_runtime.h>

// out[b,o] = max_k min(m[b,k], clamp(w[k,o],0,1)); B=1024, IN=512, OUT=256, fp32.
// Thread = 2x2 output tile, all state in named scalars (no arrays -> no scratch).
// Grid 256 blocks x 256 threads covers the full output; no K-split, no LDS.

constexpr int IN  = 512;
constexpr int OUT = 256;

__device__ __forceinline__ float clamp01(float x) {
  return fminf(fmaxf(x, 0.0f), 1.0f);   // -> v_med3_f32 with inline consts
}

struct M8 { float4 a0, a1, b0, b1; };           // rows r0,r0+1 x k..k+7
struct W8 { float2 w0,w1,w2,w3,w4,w5,w6,w7; };  // cols c0,c0+1 x k..k+7

__device__ __forceinline__ M8 load_m(const float* __restrict__ p0,
                                     const float* __restrict__ p1, int k) {
  M8 r;
  r.a0 = *reinterpret_cast<const float4*>(p0 + k);
  r.a1 = *reinterpret_cast<const float4*>(p0 + k + 4);
  r.b0 = *reinterpret_cast<const float4*>(p1 + k);
  r.b1 = *reinterpret_cast<const float4*>(p1 + k + 4);
  return r;
}

__device__ __forceinline__ W8 load_w(const float* __restrict__ pw, int k) {
  W8 r;
  r.w0 = *reinterpret_cast<const float2*>(pw + (size_t)(k + 0) * OUT);
  r.w1 = *reinterpret_cast<const float2*>(pw + (size_t)(k + 1) * OUT);
  r.w2 = *reinterpret_cast<const float2*>(pw + (size_t)(k + 2) * OUT);
  r.w3 = *reinterpret_cast<const float2*>(pw + (size_t)(k + 3) * OUT);
  r.w4 = *reinterpret_cast<const float2*>(pw + (size_t)(k + 4) * OUT);
  r.w5 = *reinterpret_cast<const float2*>(pw + (size_t)(k + 5) * OUT);
  r.w6 = *reinterpret_cast<const float2*>(pw + (size_t)(k + 6) * OUT);
  r.w7 = *reinterpret_cast<const float2*>(pw + (size_t)(k + 7) * OUT);
  return r;
}

__device__ __forceinline__ void comp(const M8& mm, const W8& ww, float4& acc) {
  // acc.x=(r0,c0) acc.y=(r0,c1) acc.z=(r1,c0) acc.w=(r1,c1)
  float cx, cy;
#define STEP(WV, MA, MB)                         \
  cx = clamp01((WV).x); cy = clamp01((WV).y);    \
  acc.x = fmaxf(acc.x, fminf((MA), cx));         \
  acc.y = fmaxf(acc.y, fminf((MA), cy));         \
  acc.z = fmaxf(acc.z, fminf((MB), cx));         \
  acc.w = fmaxf(acc.w, fminf((MB), cy));
  STEP(ww.w0, mm.a0.x, mm.b0.x)
  STEP(ww.w1, mm.a0.y, mm.b0.y)
  STEP(ww.w2, mm.a0.z, mm.b0.z)
  STEP(ww.w3, mm.a0.w, mm.b0.w)
  STEP(ww.w4, mm.a1.x, mm.b1.x)
  STEP(ww.w5, mm.a1.y, mm.b1.y)
  STEP(ww.w6, mm.a1.z, mm.b1.z)
  STEP(ww.w7, mm.a1.w, mm.b1.w)
#undef STEP
}

__global__ __launch_bounds__(256, 1)
void minmax_kernel(const float* __restrict__ m,
                   const float* __restrict__ w,
                   float* __restrict__ out) {
  const int tid = threadIdx.x;
  const int c0  = 2 * (tid & 127);                 // 2 cols per thread, 128 col-threads
  const int r0  = blockIdx.x * 4 + 2 * (tid >> 7); // 2 rows per thread, 2 row-groups

  const float* pm0 = m + (size_t)r0 * IN;          // wave-uniform address -> broadcast
  const float* pm1 = pm0 + IN;
  const float* pw  = w + c0;                       // coalesced: 512B/wave per float2 row

  float4 acc = make_float4(0.f, 0.f, 0.f, 0.f);    // results are >= 0, so 0 is a valid -inf

  // 2-deep software pipeline over 8-k chunks, all buffers named (register-resident).
  M8 mA = load_m(pm0, pm1, 0);
  W8 wA = load_w(pw, 0);
  M8 mB; W8 wB;

#pragma unroll 1
  for (int k = 0; k < IN - 16; k += 16) {
    mB = load_m(pm0, pm1, k + 8);
    wB = load_w(pw, k + 8);
    comp(mA, wA, acc);
    mA = load_m(pm0, pm1, k + 16);
    wA = load_w(pw, k + 16);
    comp(mB, wB, acc);
  }
  // epilogue: chunks IN-16 (already in A) and IN-8
  mB = load_m(pm0, pm1, IN - 8);
  wB = load_w(pw, IN - 8);
  comp(mA, wA, acc);
  comp(mB, wB, acc);

  float* po0 = out + (size_t)r0 * OUT + c0;
  float* po1 = po0 + OUT;
  *reinterpret_cast<float2*>(po0) = make_float2(acc.x, acc.y);
  *reinterpret_cast<float2*>(po1) = make_float2(acc.z, acc.w);
}

extern "C" void kernel_launch(void* const* d_in, const int* in_sizes, int n_in,
                              void* d_out, int out_size, void* d_ws, size_t ws_size,
                              hipStream_t stream) {
  (void)n_in; (void)out_size; (void)d_ws; (void)ws_size;
  const float* m = (const float*)d_in[0];
  const float* w = (const float*)d_in[1];
  float* out = (float*)d_out;
  const int B = in_sizes[0] / IN;       // 1024
  dim3 grid(B / 4);                     // 4 rows per block -> 256 blocks
  minmax_kernel<<<grid, 256, 0, stream>>>(m, w, out);
}

// Round 5
// 76.018 us; speedup vs baseline: 8.0225x; 1.2773x over previous
//
#include <hip/hip_runtime.h>

// out[b,o] = max_k min(m[b,k], clamp(w[k,o],0,1)); B=1024, IN=512, OUT=256, fp32.
// Latency-bound fix: K-split G=4 inside a 1024-thread block.
//   block = 4 rows x 256 cols, 256 blocks -> 4096 waves (16/CU, 4/SIMD).
//   thread = 1 row x 4 cols x 128 k, float4 w-loads, 2-deep named-struct pipeline.
//   partials -> 16KB LDS -> 4-way max -> coalesced store.

constexpr int IN  = 512;
constexpr int OUT = 256;
constexpr int RPB = 4;          // rows per block
constexpr int G   = 4;          // K-split groups
constexpr int KT  = IN / G;     // 128 k per thread

__device__ __forceinline__ float clamp01(float x) {
  return fminf(fmaxf(x, 0.0f), 1.0f);   // v_med3_f32
}

struct W8 { float4 k0,k1,k2,k3,k4,k5,k6,k7; };  // 8 k-rows x 4 cols
struct M8 { float4 lo, hi; };                   // 8 k of this thread's m-row

__device__ __forceinline__ M8 load_m(const float* __restrict__ pm, int k) {
  M8 r;
  r.lo = *reinterpret_cast<const float4*>(pm + k);
  r.hi = *reinterpret_cast<const float4*>(pm + k + 4);
  return r;
}

__device__ __forceinline__ W8 load_w(const float* __restrict__ pw, int k) {
  W8 r;
  r.k0 = *reinterpret_cast<const float4*>(pw + (size_t)(k + 0) * OUT);
  r.k1 = *reinterpret_cast<const float4*>(pw + (size_t)(k + 1) * OUT);
  r.k2 = *reinterpret_cast<const float4*>(pw + (size_t)(k + 2) * OUT);
  r.k3 = *reinterpret_cast<const float4*>(pw + (size_t)(k + 3) * OUT);
  r.k4 = *reinterpret_cast<const float4*>(pw + (size_t)(k + 4) * OUT);
  r.k5 = *reinterpret_cast<const float4*>(pw + (size_t)(k + 5) * OUT);
  r.k6 = *reinterpret_cast<const float4*>(pw + (size_t)(k + 6) * OUT);
  r.k7 = *reinterpret_cast<const float4*>(pw + (size_t)(k + 7) * OUT);
  return r;
}

__device__ __forceinline__ void comp(const M8& mm, const W8& ww, float4& acc) {
  float4 cw;
#define STEP(WV, MV)                          \
  cw.x = clamp01((WV).x); cw.y = clamp01((WV).y); \
  cw.z = clamp01((WV).z); cw.w = clamp01((WV).w); \
  acc.x = fmaxf(acc.x, fminf((MV), cw.x));    \
  acc.y = fmaxf(acc.y, fminf((MV), cw.y));    \
  acc.z = fmaxf(acc.z, fminf((MV), cw.z));    \
  acc.w = fmaxf(acc.w, fminf((MV), cw.w));
  STEP(ww.k0, mm.lo.x)
  STEP(ww.k1, mm.lo.y)
  STEP(ww.k2, mm.lo.z)
  STEP(ww.k3, mm.lo.w)
  STEP(ww.k4, mm.hi.x)
  STEP(ww.k5, mm.hi.y)
  STEP(ww.k6, mm.hi.z)
  STEP(ww.k7, mm.hi.w)
#undef STEP
}

__global__ __launch_bounds__(1024, 4)
void minmax_kernel(const float* __restrict__ m,
                   const float* __restrict__ w,
                   float* __restrict__ out) {
  __shared__ float part[G][RPB][OUT];          // 16 KB

  const int tid = threadIdx.x;
  const int cg  = tid & 63;                    // 64 col-groups of 4 cols
  const int r   = (tid >> 6) & 3;              // row within block
  const int ksg = tid >> 8;                    // K-split group 0..3
  const int c0  = cg * 4;
  const int row = blockIdx.x * RPB + r;

  const float* pm = m + (size_t)row * IN + ksg * KT;       // wave-uniform -> broadcast
  const float* pw = w + (size_t)(ksg * KT) * OUT + c0;     // float4 coalesced: 1KB/wave

  float4 acc = make_float4(0.f, 0.f, 0.f, 0.f);  // min(m,wc) >= 0, so 0 is safe -inf

  // 2-deep software pipeline, 8-k chunks, all state in named fields (no scratch).
  M8 mA = load_m(pm, 0);
  W8 wA = load_w(pw, 0);
  M8 mB; W8 wB;

#pragma unroll 1
  for (int k = 0; k < KT - 16; k += 16) {
    mB = load_m(pm, k + 8);
    wB = load_w(pw, k + 8);
    comp(mA, wA, acc);
    mA = load_m(pm, k + 16);
    wA = load_w(pw, k + 16);
    comp(mB, wB, acc);
  }
  mB = load_m(pm, KT - 8);
  wB = load_w(pw, KT - 8);
  comp(mA, wA, acc);
  comp(mB, wB, acc);

  // Partial results to LDS, then 4-way reduce (one output per thread).
  *reinterpret_cast<float4*>(&part[ksg][r][c0]) = acc;
  __syncthreads();

  const int rr = tid >> 8;                     // 0..3
  const int cc = tid & 255;                    // 0..255 -> conflict-free (2 lanes/bank)
  const float v0 = part[0][rr][cc];
  const float v1 = part[1][rr][cc];
  const float v2 = part[2][rr][cc];
  const float v3 = part[3][rr][cc];
  out[(size_t)(blockIdx.x * RPB + rr) * OUT + cc] =
      fmaxf(fmaxf(v0, v1), fmaxf(v2, v3));
}

extern "C" void kernel_launch(void* const* d_in, const int* in_sizes, int n_in,
                              void* d_out, int out_size, void* d_ws, size_t ws_size,
                              hipStream_t stream) {
  (void)n_in; (void)out_size; (void)d_ws; (void)ws_size;
  const float* m = (const float*)d_in[0];
  const float* w = (const float*)d_in[1];
  float* out = (float*)d_out;
  const int B = in_sizes[0] / IN;              // 1024
  dim3 grid(B / RPB);                          // 256 blocks x 1024 threads
  minmax_kernel<<<grid, 1024, 0, stream>>>(m, w, out);
}

// Round 6
// 66.324 us; speedup vs baseline: 9.1951x; 1.1462x over previous
//
#include <hip/hip_runtime.h>

// out[b,o] = max_k min(m[b,k], clamp(w[k,o],0,1)); B=1024, IN=512, OUT=256, fp32.
// Round 6: amortize w across 4 rows per thread (w->reg traffic 512MB -> 128MB),
// keep occupancy with G=8 K-split. Block = 512 thr (64 colgrp x 8 ksg) = 8 waves/CU,
// grid = 256 blocks (1/CU). Thread = 4 rows x 4 cols x KT=64. Named structs only.

constexpr int IN  = 512;
constexpr int OUT = 256;
constexpr int RPB = 4;          // rows per block == rows per thread
constexpr int G   = 8;          // K-split groups
constexpr int KT  = IN / G;     // 64 k per thread

__device__ __forceinline__ float clamp01(float x) {
  return fminf(fmaxf(x, 0.0f), 1.0f);   // v_med3_f32
}

struct W8   { float4 k0,k1,k2,k3,k4,k5,k6,k7; };           // 8 k-rows x 4 cols
struct M8x4 { float4 r0lo,r0hi,r1lo,r1hi,r2lo,r2hi,r3lo,r3hi; }; // 4 rows x 8 k

__device__ __forceinline__ M8x4 load_m(const float* __restrict__ p0,
                                       const float* __restrict__ p1,
                                       const float* __restrict__ p2,
                                       const float* __restrict__ p3, int k) {
  M8x4 r;
  r.r0lo = *reinterpret_cast<const float4*>(p0 + k);
  r.r0hi = *reinterpret_cast<const float4*>(p0 + k + 4);
  r.r1lo = *reinterpret_cast<const float4*>(p1 + k);
  r.r1hi = *reinterpret_cast<const float4*>(p1 + k + 4);
  r.r2lo = *reinterpret_cast<const float4*>(p2 + k);
  r.r2hi = *reinterpret_cast<const float4*>(p2 + k + 4);
  r.r3lo = *reinterpret_cast<const float4*>(p3 + k);
  r.r3hi = *reinterpret_cast<const float4*>(p3 + k + 4);
  return r;
}

__device__ __forceinline__ W8 load_w(const float* __restrict__ pw, int k) {
  W8 r;
  r.k0 = *reinterpret_cast<const float4*>(pw + (size_t)(k + 0) * OUT);
  r.k1 = *reinterpret_cast<const float4*>(pw + (size_t)(k + 1) * OUT);
  r.k2 = *reinterpret_cast<const float4*>(pw + (size_t)(k + 2) * OUT);
  r.k3 = *reinterpret_cast<const float4*>(pw + (size_t)(k + 3) * OUT);
  r.k4 = *reinterpret_cast<const float4*>(pw + (size_t)(k + 4) * OUT);
  r.k5 = *reinterpret_cast<const float4*>(pw + (size_t)(k + 5) * OUT);
  r.k6 = *reinterpret_cast<const float4*>(pw + (size_t)(k + 6) * OUT);
  r.k7 = *reinterpret_cast<const float4*>(pw + (size_t)(k + 7) * OUT);
  return r;
}

__device__ __forceinline__ void upd(float4& acc, float mv, const float4& cw) {
  acc.x = fmaxf(acc.x, fminf(mv, cw.x));
  acc.y = fmaxf(acc.y, fminf(mv, cw.y));
  acc.z = fmaxf(acc.z, fminf(mv, cw.z));
  acc.w = fmaxf(acc.w, fminf(mv, cw.w));
}

__device__ __forceinline__ void comp(const M8x4& mm, const W8& ww,
                                     float4& a0, float4& a1, float4& a2, float4& a3) {
  float4 cw;
#define STEPK(WV, M0, M1, M2, M3)                                   \
  cw.x = clamp01((WV).x); cw.y = clamp01((WV).y);                   \
  cw.z = clamp01((WV).z); cw.w = clamp01((WV).w);                   \
  upd(a0, (M0), cw); upd(a1, (M1), cw); upd(a2, (M2), cw); upd(a3, (M3), cw);
  STEPK(ww.k0, mm.r0lo.x, mm.r1lo.x, mm.r2lo.x, mm.r3lo.x)
  STEPK(ww.k1, mm.r0lo.y, mm.r1lo.y, mm.r2lo.y, mm.r3lo.y)
  STEPK(ww.k2, mm.r0lo.z, mm.r1lo.z, mm.r2lo.z, mm.r3lo.z)
  STEPK(ww.k3, mm.r0lo.w, mm.r1lo.w, mm.r2lo.w, mm.r3lo.w)
  STEPK(ww.k4, mm.r0hi.x, mm.r1hi.x, mm.r2hi.x, mm.r3hi.x)
  STEPK(ww.k5, mm.r0hi.y, mm.r1hi.y, mm.r2hi.y, mm.r3hi.y)
  STEPK(ww.k6, mm.r0hi.z, mm.r1hi.z, mm.r2hi.z, mm.r3hi.z)
  STEPK(ww.k7, mm.r0hi.w, mm.r1hi.w, mm.r2hi.w, mm.r3hi.w)
#undef STEPK
}

__global__ __launch_bounds__(512, 2)
void minmax_kernel(const float* __restrict__ m,
                   const float* __restrict__ w,
                   float* __restrict__ out) {
  __shared__ float part[G][RPB][OUT];          // 8*4*256*4 = 32 KB

  const int tid  = threadIdx.x;
  const int cg   = tid & 63;                   // 64 col-groups of 4 cols
  const int ksg  = tid >> 6;                   // K-split group 0..7 (wave-uniform)
  const int c0   = cg * 4;
  const int row0 = blockIdx.x * RPB;

  const float* pm0 = m + (size_t)row0 * IN + ksg * KT;   // wave-uniform -> broadcast
  const float* pm1 = pm0 + IN;
  const float* pm2 = pm1 + IN;
  const float* pm3 = pm2 + IN;
  const float* pw  = w + (size_t)(ksg * KT) * OUT + c0;  // float4 coalesced

  float4 a0 = make_float4(0.f,0.f,0.f,0.f);    // min(m, wc) >= 0, 0 is safe -inf
  float4 a1 = a0, a2 = a0, a3 = a0;

  // 2-deep pipeline over 8-k chunks; all state named (register-resident).
  M8x4 mA = load_m(pm0, pm1, pm2, pm3, 0);
  W8   wA = load_w(pw, 0);
  M8x4 mB; W8 wB;

#pragma unroll 1
  for (int k = 0; k < KT - 16; k += 16) {
    mB = load_m(pm0, pm1, pm2, pm3, k + 8);
    wB = load_w(pw, k + 8);
    comp(mA, wA, a0, a1, a2, a3);
    mA = load_m(pm0, pm1, pm2, pm3, k + 16);
    wA = load_w(pw, k + 16);
    comp(mB, wB, a0, a1, a2, a3);
  }
  mB = load_m(pm0, pm1, pm2, pm3, KT - 8);
  wB = load_w(pw, KT - 8);
  comp(mA, wA, a0, a1, a2, a3);
  comp(mB, wB, a0, a1, a2, a3);

  // Partials -> LDS (float4 rows, full-bandwidth, no conflicts).
  *reinterpret_cast<float4*>(&part[ksg][0][c0]) = a0;
  *reinterpret_cast<float4*>(&part[ksg][1][c0]) = a1;
  *reinterpret_cast<float4*>(&part[ksg][2][c0]) = a2;
  *reinterpret_cast<float4*>(&part[ksg][3][c0]) = a3;
  __syncthreads();

  // 512 threads x 2 outputs: 8-way max reduce, coalesced float2 store.
  const int o  = tid * 2;
  const int rr = o >> 8;
  const int cc = o & 255;
  float2 v = *reinterpret_cast<const float2*>(&part[0][rr][cc]);
#define RED(g) { float2 t = *reinterpret_cast<const float2*>(&part[(g)][rr][cc]); \
                 v.x = fmaxf(v.x, t.x); v.y = fmaxf(v.y, t.y); }
  RED(1) RED(2) RED(3) RED(4) RED(5) RED(6) RED(7)
#undef RED
  *reinterpret_cast<float2*>(&out[(size_t)(row0 + rr) * OUT + cc]) = v;
}

extern "C" void kernel_launch(void* const* d_in, const int* in_sizes, int n_in,
                              void* d_out, int out_size, void* d_ws, size_t ws_size,
                              hipStream_t stream) {
  (void)n_in; (void)out_size; (void)d_ws; (void)ws_size;
  const float* m = (const float*)d_in[0];
  const float* w = (const float*)d_in[1];
  float* out = (float*)d_out;
  const int B = in_sizes[0] / IN;              // 1024
  dim3 grid(B / RPB);                          // 256 blocks x 512 threads
  minmax_kernel<<<grid, 512, 0, stream>>>(m, w, out);
}

// Round 7
// 66.287 us; speedup vs baseline: 9.2003x; 1.0006x over previous
//
#include <hip/hip_runtime.h>
#include <cstdint>

// out[b,o] = max_k min(m[b,k], clamp(w[k,o],0,1)); B=1024, IN=512, OUT=256, fp32.
// Round 7: packed fp16 (threshold is 2e-2; fp16 err <= ~5e-4).
//   prep: wc16 = half(clamp01(w)) [256KB], msp = splat-pair(half(m)) [2MB] in d_ws.
//   main: block=1024 (32 colgrp x 32 ksg), thread = 4 rows x 8 cols x KT=16,
//         v_pk_min/max_f16 via clang elementwise builtins, 64KB LDS h2 reduce.
// Fallback to proven fp32 kernel if ws_size < 2.3MB.

typedef _Float16 h2 __attribute__((ext_vector_type(2)));
typedef _Float16 h8 __attribute__((ext_vector_type(8)));

constexpr int IN  = 512;
constexpr int OUT = 256;

static __device__ __forceinline__ uint32_t bc_u32(h2 v) { return __builtin_bit_cast(uint32_t, v); }
static __device__ __forceinline__ h2 bc_h2(uint32_t v)  { return __builtin_bit_cast(h2, v); }

// ---------------- prep kernels ----------------
__global__ void prep_msp(const float* __restrict__ m, uint32_t* __restrict__ msp, int n4) {
  int i = blockIdx.x * blockDim.x + threadIdx.x;
  if (i >= n4) return;
  float4 v = reinterpret_cast<const float4*>(m)[i];
  uint4 o;
  { h2 t = { (_Float16)v.x, (_Float16)v.x }; o.x = bc_u32(t); }
  { h2 t = { (_Float16)v.y, (_Float16)v.y }; o.y = bc_u32(t); }
  { h2 t = { (_Float16)v.z, (_Float16)v.z }; o.z = bc_u32(t); }
  { h2 t = { (_Float16)v.w, (_Float16)v.w }; o.w = bc_u32(t); }
  reinterpret_cast<uint4*>(msp)[i] = o;
}

__global__ void prep_wc(const float* __restrict__ w, uint32_t* __restrict__ wc, int n4) {
  int i = blockIdx.x * blockDim.x + threadIdx.x;
  if (i >= n4) return;
  float4 v = reinterpret_cast<const float4*>(w)[i];
  float a = fminf(fmaxf(v.x, 0.f), 1.f);
  float b = fminf(fmaxf(v.y, 0.f), 1.f);
  float c = fminf(fmaxf(v.z, 0.f), 1.f);
  float d = fminf(fmaxf(v.w, 0.f), 1.f);
  h2 p0 = { (_Float16)a, (_Float16)b };
  h2 p1 = { (_Float16)c, (_Float16)d };
  uint2 o = { bc_u32(p0), bc_u32(p1) };
  reinterpret_cast<uint2*>(wc)[i] = o;
}

// ---------------- fp16 main kernel ----------------
struct W4 { h8 k0, k1, k2, k3; };     // 4 k-rows x 8 cols
struct M4 { uint4 r0, r1, r2, r3; };  // 4 rows x 4 k-splat-pairs
struct A8 { h2 c0, c1, c2, c3; };     // 8-col accumulator (4 pairs)

static __device__ __forceinline__ W4 load_w4(const _Float16* __restrict__ pw, int k) {
  W4 r;
  r.k0 = *reinterpret_cast<const h8*>(pw + (k + 0) * OUT);
  r.k1 = *reinterpret_cast<const h8*>(pw + (k + 1) * OUT);
  r.k2 = *reinterpret_cast<const h8*>(pw + (k + 2) * OUT);
  r.k3 = *reinterpret_cast<const h8*>(pw + (k + 3) * OUT);
  return r;
}
static __device__ __forceinline__ M4 load_m4(const uint32_t* __restrict__ pm, int k) {
  M4 r;
  r.r0 = *reinterpret_cast<const uint4*>(pm + k);
  r.r1 = *reinterpret_cast<const uint4*>(pm + k + IN);
  r.r2 = *reinterpret_cast<const uint4*>(pm + k + 2 * IN);
  r.r3 = *reinterpret_cast<const uint4*>(pm + k + 3 * IN);
  return r;
}

static __device__ __forceinline__ void comp4(const W4& wv, const M4& ms,
                                             A8& a0, A8& a1, A8& a2, A8& a3) {
#define UPD(A, MP)                                                              \
  A.c0 = __builtin_elementwise_max(A.c0, __builtin_elementwise_min(MP, w0));    \
  A.c1 = __builtin_elementwise_max(A.c1, __builtin_elementwise_min(MP, w1));    \
  A.c2 = __builtin_elementwise_max(A.c2, __builtin_elementwise_min(MP, w2));    \
  A.c3 = __builtin_elementwise_max(A.c3, __builtin_elementwise_min(MP, w3));
#define KROW(HK, CMP)                                                           \
  {                                                                             \
    h2 w0 = { (HK)[0], (HK)[1] }, w1 = { (HK)[2], (HK)[3] },                    \
       w2 = { (HK)[4], (HK)[5] }, w3 = { (HK)[6], (HK)[7] };                    \
    h2 mp0 = bc_h2(ms.r0.CMP), mp1 = bc_h2(ms.r1.CMP),                          \
       mp2 = bc_h2(ms.r2.CMP), mp3 = bc_h2(ms.r3.CMP);                          \
    UPD(a0, mp0) UPD(a1, mp1) UPD(a2, mp2) UPD(a3, mp3)                         \
  }
  KROW(wv.k0, x) KROW(wv.k1, y) KROW(wv.k2, z) KROW(wv.k3, w)
#undef KROW
#undef UPD
}

__global__ __launch_bounds__(1024, 1)
void minmax_h2(const uint32_t* __restrict__ msp, const _Float16* __restrict__ wc,
               float* __restrict__ out) {
  __shared__ uint32_t part[32][4][128];       // exactly 64 KB
  const int tid  = threadIdx.x;
  const int cg   = tid & 31;                  // 32 col-groups of 8 cols
  const int ksg  = tid >> 5;                  // 32 K-split groups, KT=16
  const int row0 = blockIdx.x * 4;
  const int k0   = ksg * 16;

  const uint32_t* pm = msp + (size_t)row0 * IN + k0;     // wave-uniform -> broadcast
  const _Float16* pw = wc + (size_t)k0 * OUT + cg * 8;   // 16B/lane coalesced

  A8 a0 = {}, a1 = {}, a2 = {}, a3 = {};      // zeros (min(m,wc) >= 0)

  // KT=16 as 4 chunks of 4 k, fully unrolled 2-deep pipeline, all state named.
  W4 wA = load_w4(pw, 0);  M4 mA = load_m4(pm, 0);
  W4 wB = load_w4(pw, 4);  M4 mB = load_m4(pm, 4);
  comp4(wA, mA, a0, a1, a2, a3);
  wA = load_w4(pw, 8);  mA = load_m4(pm, 8);
  comp4(wB, mB, a0, a1, a2, a3);
  wB = load_w4(pw, 12); mB = load_m4(pm, 12);
  comp4(wA, mA, a0, a1, a2, a3);
  comp4(wB, mB, a0, a1, a2, a3);

  uint4 s0 = { bc_u32(a0.c0), bc_u32(a0.c1), bc_u32(a0.c2), bc_u32(a0.c3) };
  uint4 s1 = { bc_u32(a1.c0), bc_u32(a1.c1), bc_u32(a1.c2), bc_u32(a1.c3) };
  uint4 s2 = { bc_u32(a2.c0), bc_u32(a2.c1), bc_u32(a2.c2), bc_u32(a2.c3) };
  uint4 s3 = { bc_u32(a3.c0), bc_u32(a3.c1), bc_u32(a3.c2), bc_u32(a3.c3) };
  *reinterpret_cast<uint4*>(&part[ksg][0][cg * 4]) = s0;
  *reinterpret_cast<uint4*>(&part[ksg][1][cg * 4]) = s1;
  *reinterpret_cast<uint4*>(&part[ksg][2][cg * 4]) = s2;
  *reinterpret_cast<uint4*>(&part[ksg][3][cg * 4]) = s3;
  __syncthreads();

  // 512 threads reduce 32 partials each (h2-packed, 2-way banks = free).
  if (tid < 512) {
    const int r  = tid >> 7;
    const int op = tid & 127;
    h2 v = bc_h2(part[0][r][op]);
#pragma unroll
    for (int g = 1; g < 32; ++g)
      v = __builtin_elementwise_max(v, bc_h2(part[g][r][op]));
    float2 f = { (float)v[0], (float)v[1] };
    *reinterpret_cast<float2*>(&out[(size_t)(row0 + r) * OUT + op * 2]) = f;
  }
}

// ---------------- fp32 fallback (proven round-6 kernel) ----------------
constexpr int RPB = 4;
constexpr int G   = 8;
constexpr int KT  = IN / G;

__device__ __forceinline__ float clamp01(float x) { return fminf(fmaxf(x, 0.0f), 1.0f); }

struct W8f   { float4 k0,k1,k2,k3,k4,k5,k6,k7; };
struct M8x4f { float4 r0lo,r0hi,r1lo,r1hi,r2lo,r2hi,r3lo,r3hi; };

__device__ __forceinline__ M8x4f load_mf(const float* p0, const float* p1,
                                         const float* p2, const float* p3, int k) {
  M8x4f r;
  r.r0lo = *reinterpret_cast<const float4*>(p0 + k); r.r0hi = *reinterpret_cast<const float4*>(p0 + k + 4);
  r.r1lo = *reinterpret_cast<const float4*>(p1 + k); r.r1hi = *reinterpret_cast<const float4*>(p1 + k + 4);
  r.r2lo = *reinterpret_cast<const float4*>(p2 + k); r.r2hi = *reinterpret_cast<const float4*>(p2 + k + 4);
  r.r3lo = *reinterpret_cast<const float4*>(p3 + k); r.r3hi = *reinterpret_cast<const float4*>(p3 + k + 4);
  return r;
}
__device__ __forceinline__ W8f load_wf(const float* pw, int k) {
  W8f r;
  r.k0 = *reinterpret_cast<const float4*>(pw + (size_t)(k + 0) * OUT);
  r.k1 = *reinterpret_cast<const float4*>(pw + (size_t)(k + 1) * OUT);
  r.k2 = *reinterpret_cast<const float4*>(pw + (size_t)(k + 2) * OUT);
  r.k3 = *reinterpret_cast<const float4*>(pw + (size_t)(k + 3) * OUT);
  r.k4 = *reinterpret_cast<const float4*>(pw + (size_t)(k + 4) * OUT);
  r.k5 = *reinterpret_cast<const float4*>(pw + (size_t)(k + 5) * OUT);
  r.k6 = *reinterpret_cast<const float4*>(pw + (size_t)(k + 6) * OUT);
  r.k7 = *reinterpret_cast<const float4*>(pw + (size_t)(k + 7) * OUT);
  return r;
}
__device__ __forceinline__ void updf(float4& acc, float mv, const float4& cw) {
  acc.x = fmaxf(acc.x, fminf(mv, cw.x)); acc.y = fmaxf(acc.y, fminf(mv, cw.y));
  acc.z = fmaxf(acc.z, fminf(mv, cw.z)); acc.w = fmaxf(acc.w, fminf(mv, cw.w));
}
__device__ __forceinline__ void compf(const M8x4f& mm, const W8f& ww,
                                      float4& a0, float4& a1, float4& a2, float4& a3) {
  float4 cw;
#define STEPK(WV, M0, M1, M2, M3)                                   \
  cw.x = clamp01((WV).x); cw.y = clamp01((WV).y);                   \
  cw.z = clamp01((WV).z); cw.w = clamp01((WV).w);                   \
  updf(a0, (M0), cw); updf(a1, (M1), cw); updf(a2, (M2), cw); updf(a3, (M3), cw);
  STEPK(ww.k0, mm.r0lo.x, mm.r1lo.x, mm.r2lo.x, mm.r3lo.x)
  STEPK(ww.k1, mm.r0lo.y, mm.r1lo.y, mm.r2lo.y, mm.r3lo.y)
  STEPK(ww.k2, mm.r0lo.z, mm.r1lo.z, mm.r2lo.z, mm.r3lo.z)
  STEPK(ww.k3, mm.r0lo.w, mm.r1lo.w, mm.r2lo.w, mm.r3lo.w)
  STEPK(ww.k4, mm.r0hi.x, mm.r1hi.x, mm.r2hi.x, mm.r3hi.x)
  STEPK(ww.k5, mm.r0hi.y, mm.r1hi.y, mm.r2hi.y, mm.r3hi.y)
  STEPK(ww.k6, mm.r0hi.z, mm.r1hi.z, mm.r2hi.z, mm.r3hi.z)
  STEPK(ww.k7, mm.r0hi.w, mm.r1hi.w, mm.r2hi.w, mm.r3hi.w)
#undef STEPK
}

__global__ __launch_bounds__(512, 2)
void minmax_f32(const float* __restrict__ m, const float* __restrict__ w,
                float* __restrict__ out) {
  __shared__ float part[G][RPB][OUT];
  const int tid  = threadIdx.x;
  const int cgf  = tid & 63;
  const int ksgf = tid >> 6;
  const int c0   = cgf * 4;
  const int row0 = blockIdx.x * RPB;
  const float* pm0 = m + (size_t)row0 * IN + ksgf * KT;
  const float* pm1 = pm0 + IN;
  const float* pm2 = pm1 + IN;
  const float* pm3 = pm2 + IN;
  const float* pw  = w + (size_t)(ksgf * KT) * OUT + c0;
  float4 a0 = make_float4(0.f,0.f,0.f,0.f), a1 = a0, a2 = a0, a3 = a0;
  M8x4f mA = load_mf(pm0, pm1, pm2, pm3, 0);
  W8f   wA = load_wf(pw, 0);
  M8x4f mB; W8f wB;
#pragma unroll 1
  for (int k = 0; k < KT - 16; k += 16) {
    mB = load_mf(pm0, pm1, pm2, pm3, k + 8);  wB = load_wf(pw, k + 8);
    compf(mA, wA, a0, a1, a2, a3);
    mA = load_mf(pm0, pm1, pm2, pm3, k + 16); wA = load_wf(pw, k + 16);
    compf(mB, wB, a0, a1, a2, a3);
  }
  mB = load_mf(pm0, pm1, pm2, pm3, KT - 8);  wB = load_wf(pw, KT - 8);
  compf(mA, wA, a0, a1, a2, a3);
  compf(mB, wB, a0, a1, a2, a3);
  *reinterpret_cast<float4*>(&part[ksgf][0][c0]) = a0;
  *reinterpret_cast<float4*>(&part[ksgf][1][c0]) = a1;
  *reinterpret_cast<float4*>(&part[ksgf][2][c0]) = a2;
  *reinterpret_cast<float4*>(&part[ksgf][3][c0]) = a3;
  __syncthreads();
  const int o  = tid * 2;
  const int rr = o >> 8;
  const int cc = o & 255;
  float2 v = *reinterpret_cast<const float2*>(&part[0][rr][cc]);
#define RED(g) { float2 t = *reinterpret_cast<const float2*>(&part[(g)][rr][cc]); \
                 v.x = fmaxf(v.x, t.x); v.y = fmaxf(v.y, t.y); }
  RED(1) RED(2) RED(3) RED(4) RED(5) RED(6) RED(7)
#undef RED
  *reinterpret_cast<float2*>(&out[(size_t)(row0 + rr) * OUT + cc]) = v;
}

// ---------------- launch ----------------
extern "C" void kernel_launch(void* const* d_in, const int* in_sizes, int n_in,
                              void* d_out, int out_size, void* d_ws, size_t ws_size,
                              hipStream_t stream) {
  (void)n_in; (void)out_size;
  const float* m = (const float*)d_in[0];
  const float* w = (const float*)d_in[1];
  float* out = (float*)d_out;
  const int B = in_sizes[0] / IN;                      // 1024
  const size_t msp_bytes = (size_t)B * IN * 4;         // 2 MB
  const size_t wc_bytes  = (size_t)IN * OUT * 2;       // 256 KB

  if (ws_size >= msp_bytes + wc_bytes) {
    uint32_t* msp = (uint32_t*)d_ws;
    uint32_t* wcu = (uint32_t*)((char*)d_ws + msp_bytes);
    _Float16* wch = (_Float16*)wcu;
    const int n4m = B * IN / 4;                        // 131072
    const int n4w = IN * OUT / 4;                      // 32768
    prep_msp<<<(n4m + 255) / 256, 256, 0, stream>>>(m, msp, n4m);
    prep_wc <<<(n4w + 255) / 256, 256, 0, stream>>>(w, wcu, n4w);
    minmax_h2<<<B / 4, 1024, 0, stream>>>(msp, wch, out);
  } else {
    minmax_f32<<<B / RPB, 512, 0, stream>>>(m, w, out);
  }
}

// Round 9
// 64.922 us; speedup vs baseline: 9.3937x; 1.0210x over previous
//
#include <hip/hip_runtime.h>
#include <cstdint>

// out[b,o] = max_k min(m[b,k], clamp(w[k,o],0,1)); B=1024, IN=512, OUT=256, fp32.
// Round 9: round-8 kernel with the cvt_pkrtz return-type fix (bit_cast to h2).
// Single fused kernel, fp16 packed compute, on-the-fly convert:
//   w: float4 load -> med3 clamp -> v_cvt_pkrtz (2 cols/inst)
//   m: broadcast float4 load -> cvt_pkrtz(m,m) = splat-pair in 1 inst
// Thread = 4 rows x 4 cols x KT=32; block = 512 (32 colgrp x 16 ksg);
// grid = 512 (2 blocks/CU, 4 waves/SIMD). 16KB LDS h2 partial reduce.

typedef _Float16 h2 __attribute__((ext_vector_type(2)));

constexpr int IN  = 512;
constexpr int OUT = 256;
constexpr int KSG = 16;          // K-split groups per block
constexpr int KT  = IN / KSG;    // 32 k per thread
constexpr int CPB = 128;         // cols per block
constexpr int RPB = 4;           // rows per block

static __device__ __forceinline__ float clamp01(float x) {
  return fminf(fmaxf(x, 0.0f), 1.0f);          // v_med3_f32
}
static __device__ __forceinline__ uint32_t bc_u32(h2 v) { return __builtin_bit_cast(uint32_t, v); }
static __device__ __forceinline__ h2 bc_h2(uint32_t v)  { return __builtin_bit_cast(h2, v); }
static __device__ __forceinline__ h2 pkrtz(float a, float b) {
  return __builtin_bit_cast(h2, __builtin_amdgcn_cvt_pkrtz(a, b));
}

struct Wf { float4 k0, k1, k2, k3; };   // 4 k-rows x 4 cols fp32
struct Mf { float4 r0, r1, r2, r3; };   // 4 rows x 4 k fp32

static __device__ __forceinline__ Wf load_w(const float* __restrict__ pw, int k) {
  Wf r;
  r.k0 = *reinterpret_cast<const float4*>(pw + (size_t)(k + 0) * OUT);
  r.k1 = *reinterpret_cast<const float4*>(pw + (size_t)(k + 1) * OUT);
  r.k2 = *reinterpret_cast<const float4*>(pw + (size_t)(k + 2) * OUT);
  r.k3 = *reinterpret_cast<const float4*>(pw + (size_t)(k + 3) * OUT);
  return r;
}
static __device__ __forceinline__ Mf load_m(const float* __restrict__ p0,
                                            const float* __restrict__ p1,
                                            const float* __restrict__ p2,
                                            const float* __restrict__ p3, int k) {
  Mf r;
  r.r0 = *reinterpret_cast<const float4*>(p0 + k);
  r.r1 = *reinterpret_cast<const float4*>(p1 + k);
  r.r2 = *reinterpret_cast<const float4*>(p2 + k);
  r.r3 = *reinterpret_cast<const float4*>(p3 + k);
  return r;
}

// acc: 4 rows x (lo,hi) h2 pairs, passed as named refs (no arrays -> no scratch).
static __device__ __forceinline__ void comp(const Wf& wv, const Mf& mf,
                                            h2& a0l, h2& a0h, h2& a1l, h2& a1h,
                                            h2& a2l, h2& a2h, h2& a3l, h2& a3h) {
#define KSTEP(WK, M0, M1, M2, M3)                                              \
  {                                                                            \
    float c0 = clamp01((WK).x), c1 = clamp01((WK).y);                          \
    float c2 = clamp01((WK).z), c3 = clamp01((WK).w);                          \
    h2 wlo = pkrtz(c0, c1);                                                    \
    h2 whi = pkrtz(c2, c3);                                                    \
    h2 s0 = pkrtz((M0), (M0));                                                 \
    h2 s1 = pkrtz((M1), (M1));                                                 \
    h2 s2 = pkrtz((M2), (M2));                                                 \
    h2 s3 = pkrtz((M3), (M3));                                                 \
    a0l = __builtin_elementwise_max(a0l, __builtin_elementwise_min(s0, wlo));  \
    a0h = __builtin_elementwise_max(a0h, __builtin_elementwise_min(s0, whi));  \
    a1l = __builtin_elementwise_max(a1l, __builtin_elementwise_min(s1, wlo));  \
    a1h = __builtin_elementwise_max(a1h, __builtin_elementwise_min(s1, whi));  \
    a2l = __builtin_elementwise_max(a2l, __builtin_elementwise_min(s2, wlo));  \
    a2h = __builtin_elementwise_max(a2h, __builtin_elementwise_min(s2, whi));  \
    a3l = __builtin_elementwise_max(a3l, __builtin_elementwise_min(s3, wlo));  \
    a3h = __builtin_elementwise_max(a3h, __builtin_elementwise_min(s3, whi));  \
  }
  KSTEP(wv.k0, mf.r0.x, mf.r1.x, mf.r2.x, mf.r3.x)
  KSTEP(wv.k1, mf.r0.y, mf.r1.y, mf.r2.y, mf.r3.y)
  KSTEP(wv.k2, mf.r0.z, mf.r1.z, mf.r2.z, mf.r3.z)
  KSTEP(wv.k3, mf.r0.w, mf.r1.w, mf.r2.w, mf.r3.w)
#undef KSTEP
}

__global__ __launch_bounds__(512, 4)
void minmax_fused(const float* __restrict__ m, const float* __restrict__ w,
                  float* __restrict__ out) {
  __shared__ uint32_t part[KSG][RPB][CPB / 2];   // 16 KB

  const int tid  = threadIdx.x;
  const int cg   = tid & 31;                     // 32 col-groups of 4 cols
  const int ksg  = tid >> 5;                     // 16 K-split groups (2 per wave)
  const int row0 = (blockIdx.x >> 1) * RPB;
  const int c0b  = (blockIdx.x & 1) * CPB;
  const int k0   = ksg * KT;

  const float* pm0 = m + (size_t)row0 * IN + k0;           // 2-way broadcast/wave
  const float* pm1 = pm0 + IN;
  const float* pm2 = pm1 + IN;
  const float* pm3 = pm2 + IN;
  const float* pw  = w + (size_t)k0 * OUT + c0b + cg * 4;  // 512B contiguous/half-wave

  h2 a0l = {}, a0h = {}, a1l = {}, a1h = {};
  h2 a2l = {}, a2h = {}, a3l = {}, a3h = {};     // zeros safe: min(m,wc) >= 0

  // 2-deep pipeline over 4-k chunks, all state in named structs.
  Wf wA = load_w(pw, 0);
  Mf mA = load_m(pm0, pm1, pm2, pm3, 0);
  Wf wB; Mf mB;

#pragma unroll 1
  for (int k = 0; k < KT - 8; k += 8) {          // k = 0, 8, 16
    wB = load_w(pw, k + 4);
    mB = load_m(pm0, pm1, pm2, pm3, k + 4);
    comp(wA, mA, a0l, a0h, a1l, a1h, a2l, a2h, a3l, a3h);
    wA = load_w(pw, k + 8);
    mA = load_m(pm0, pm1, pm2, pm3, k + 8);
    comp(wB, mB, a0l, a0h, a1l, a1h, a2l, a2h, a3l, a3h);
  }
  wB = load_w(pw, KT - 4);
  mB = load_m(pm0, pm1, pm2, pm3, KT - 4);
  comp(wA, mA, a0l, a0h, a1l, a1h, a2l, a2h, a3l, a3h);
  comp(wB, mB, a0l, a0h, a1l, a1h, a2l, a2h, a3l, a3h);

  // Partials -> LDS as packed h2 (uint2 per row).
  const int cu0 = cg * 2;
  *reinterpret_cast<uint2*>(&part[ksg][0][cu0]) = make_uint2(bc_u32(a0l), bc_u32(a0h));
  *reinterpret_cast<uint2*>(&part[ksg][1][cu0]) = make_uint2(bc_u32(a1l), bc_u32(a1h));
  *reinterpret_cast<uint2*>(&part[ksg][2][cu0]) = make_uint2(bc_u32(a2l), bc_u32(a2h));
  *reinterpret_cast<uint2*>(&part[ksg][3][cu0]) = make_uint2(bc_u32(a3l), bc_u32(a3h));
  __syncthreads();

  // 256 threads: each reduces one h2 over 16 partials (2-way banks = free),
  // converts to f32, coalesced float2 store.
  if (tid < 256) {
    const int r  = tid >> 6;                     // 0..3
    const int cu = tid & 63;                     // 0..63 -> cols 2*cu, 2*cu+1
    h2 v = bc_h2(part[0][r][cu]);
#pragma unroll
    for (int g = 1; g < KSG; ++g)
      v = __builtin_elementwise_max(v, bc_h2(part[g][r][cu]));
    float2 f = { (float)v[0], (float)v[1] };
    *reinterpret_cast<float2*>(&out[(size_t)(row0 + r) * OUT + c0b + cu * 2]) = f;
  }
}

extern "C" void kernel_launch(void* const* d_in, const int* in_sizes, int n_in,
                              void* d_out, int out_size, void* d_ws, size_t ws_size,
                              hipStream_t stream) {
  (void)n_in; (void)out_size; (void)d_ws; (void)ws_size;
  const float* m = (const float*)d_in[0];
  const float* w = (const float*)d_in[1];
  float* out = (float*)d_out;
  const int B = in_sizes[0] / IN;                // 1024
  dim3 grid((B / RPB) * (OUT / CPB));            // 256 * 2 = 512 blocks
  minmax_fused<<<grid, 512, 0, stream>>>(m, w, out);
}

// Round 10
// 60.991 us; speedup vs baseline: 9.9992x; 1.0645x over previous
//
#include <hip/hip_runtime.h>
#include <cstdint>

// out[b,o] = max_k min(m[b,k], clamp(w[k,o],0,1)); B=1024, IN=512, OUT=256, fp32.
// Round 10: EXACT early-exit via bucket-descending traversal.
//   Per block (one row b): 32-bin counting sort of m-row in LDS (descending
//   buckets), then walk positions in chunks of 8; after each chunk, block-votes
//   acc >= (next bucket's upper bound) -> all remaining terms <= acc -> stop.
//   E[terms] ~ 40-90 of 512 on this data; worst case = full walk (bounded).
// One-shot flag slot per vote (64 slots, never reset) -> no LDS races.

constexpr int IN  = 512;
constexpr int OUT = 256;

static __device__ __forceinline__ float clamp01(float x) {
  return fminf(fmaxf(x, 0.0f), 1.0f);      // v_med3_f32
}

__global__ __launch_bounds__(256, 4)
void minmax_topk(const float* __restrict__ m, const float* __restrict__ w,
                 float* __restrict__ out) {
  __shared__ int   cnt[32];
  __shared__ int   start[32];
  __shared__ int   ord[IN];      // position -> k index (bucket-descending)
  __shared__ float mv[IN];       // position -> m value
  __shared__ int   flags[IN / 8];

  const int tid = threadIdx.x;
  const int b   = blockIdx.x;
  const float* mrow = m + (size_t)b * IN;

  if (tid < 32) cnt[tid] = 0;
  if (tid < IN / 8) flags[tid] = 1;
  __syncthreads();

  // Each thread owns elements tid and tid+256.
  const float v0 = mrow[tid];
  const float v1 = mrow[tid + 256];
  const int q0 = min((int)(v0 * 32.0f), 31);
  const int q1 = min((int)(v1 * 32.0f), 31);
  atomicAdd(&cnt[q0], 1);
  atomicAdd(&cnt[q1], 1);
  __syncthreads();

  if (tid == 0) {                 // descending-bucket offsets (bucket 31 first)
    int off = 0;
    for (int q = 31; q >= 0; --q) { start[q] = off; off += cnt[q]; }
  }
  __syncthreads();

  {                               // scatter (within-bucket order arbitrary)
    int p0 = atomicAdd(&start[q0], 1); ord[p0] = tid;       mv[p0] = v0;
    int p1 = atomicAdd(&start[q1], 1); ord[p1] = tid + 256; mv[p1] = v1;
  }
  __syncthreads();

  float acc = 0.0f;               // min(m,wc) >= 0, so 0 is a safe identity
  int p = 0;
  while (true) {
    // ---- chunk of 8, all named scalars (no register arrays) ----
    const float m0 = mv[p + 0]; const int i0 = ord[p + 0];
    const float m1 = mv[p + 1]; const int i1 = ord[p + 1];
    const float m2 = mv[p + 2]; const int i2 = ord[p + 2];
    const float m3 = mv[p + 3]; const int i3 = ord[p + 3];
    const float m4 = mv[p + 4]; const int i4 = ord[p + 4];
    const float m5 = mv[p + 5]; const int i5 = ord[p + 5];
    const float m6 = mv[p + 6]; const int i6 = ord[p + 6];
    const float m7 = mv[p + 7]; const int i7 = ord[p + 7];
    const float w0 = w[(size_t)i0 * OUT + tid];
    const float w1 = w[(size_t)i1 * OUT + tid];
    const float w2 = w[(size_t)i2 * OUT + tid];
    const float w3 = w[(size_t)i3 * OUT + tid];
    const float w4 = w[(size_t)i4 * OUT + tid];
    const float w5 = w[(size_t)i5 * OUT + tid];
    const float w6 = w[(size_t)i6 * OUT + tid];
    const float w7 = w[(size_t)i7 * OUT + tid];
    acc = fmaxf(acc, fminf(m0, clamp01(w0)));
    acc = fmaxf(acc, fminf(m1, clamp01(w1)));
    acc = fmaxf(acc, fminf(m2, clamp01(w2)));
    acc = fmaxf(acc, fminf(m3, clamp01(w3)));
    acc = fmaxf(acc, fminf(m4, clamp01(w4)));
    acc = fmaxf(acc, fminf(m5, clamp01(w5)));
    acc = fmaxf(acc, fminf(m6, clamp01(w6)));
    acc = fmaxf(acc, fminf(m7, clamp01(w7)));

    p += 8;
    if (p >= IN) break;           // uniform

    // Upper bound on every remaining m: next position's bucket ceiling.
    const int   qn    = min((int)(mv[p] * 32.0f), 31);
    const float bound = (float)(qn + 1) * 0.03125f;
    const int   slot  = (p >> 3) - 1;       // one-shot slot per vote
    if (acc < bound) flags[slot] = 0;       // pre-barrier writes only
    __syncthreads();
    const int done = flags[slot];           // uniform (no post-barrier writers)
    if (done) break;                        // uniform
  }

  out[(size_t)b * OUT + tid] = acc;
}

extern "C" void kernel_launch(void* const* d_in, const int* in_sizes, int n_in,
                              void* d_out, int out_size, void* d_ws, size_t ws_size,
                              hipStream_t stream) {
  (void)n_in; (void)out_size; (void)d_ws; (void)ws_size;
  const float* m = (const float*)d_in[0];
  const float* w = (const float*)d_in[1];
  float* out = (float*)d_out;
  const int B = in_sizes[0] / IN;           // 1024 blocks, one row each
  minmax_topk<<<dim3(B), 256, 0, stream>>>(m, w, out);
}